// Round 1
// 114.890 us; speedup vs baseline: 1.0344x; 1.0344x over previous
//
#include <hip/hip_runtime.h>

// Tricubic B-spline evaluation, p=3, n_ctrl=32 per dim, open-uniform knots.
// queries: [Q,3] f32 in [0,1); control_points: [32^3, 3] f32; out: [Q,3] f32.
//
// Round 13: 1 lane = 1 query (was 4 lanes/query). Quad-coherent 64B line
// gathers preserved via global_load_lds staging (per-lane global src addr,
// linear LDS dest); span indices redistributed with ds_bpermute. LDS line
// stride 1040 (=1024+16) rotates the bank-quad slot per line so the eval
// ds_read_b128 pattern is uniform across all 8 bank groups (8 lanes/slot =
// 128B/cy floor) while keeping x-offset == chunk index (static acc indexing).
// Numerics identical to round 12: int8 tables, byte->fp16 via v_perm
// (0x6400|b = 1024+b exact), v_dot2_f32_f16 core, sumw bias cancellation.

#define NCTRL 32
#define NSEG 29
#define SCALE (5.5f / 127.0f)
#define INV_SCALE (127.0f / 5.5f)

typedef unsigned int u32x4 __attribute__((ext_vector_type(4)));
typedef _Float16 h2 __attribute__((ext_vector_type(2)));
using native_h2 = decltype(__builtin_amdgcn_cvt_pkrtz(0.0f, 0.0f));

__device__ __forceinline__ h2 pkrtz(float a, float b) {
    return __builtin_bit_cast(h2, __builtin_amdgcn_cvt_pkrtz(a, b));
}
__device__ __forceinline__ float fdot2f(h2 a, h2 b, float c) {
    return __builtin_amdgcn_fdot2(__builtin_bit_cast(native_h2, a),
                                  __builtin_bit_cast(native_h2, b), c, false);
}
__device__ __forceinline__ h2 permh(unsigned int d, unsigned int sel) {
    return __builtin_bit_cast(h2, __builtin_amdgcn_perm(0x64646464u, d, sel));
}

// Division-free Cox-de Boor weights in knot units (scale-invariant).
__device__ __forceinline__ void basis_w(float U, float ft, float N[4]) {
    float x  = U - ft;
    float r1 = 1.0f - x;
    float km1 = fmaxf(ft - 1.0f, 0.0f);
    float km2 = fmaxf(ft - 2.0f, 0.0f);
    float kp2 = fminf(ft + 2.0f, (float)NSEG);
    float kp3 = fminf(ft + 3.0f, (float)NSEG);
    float l2 = U - km1, l3 = U - km2;
    float r2 = kp2 - U, r3 = kp3 - U;
    float N0 = r1, N1 = x;
    float rcp20 = __builtin_amdgcn_rcpf(ft + 1.0f - km1);
    float rcp21 = __builtin_amdgcn_rcpf(kp2 - ft);
    float temp  = N0 * rcp20;
    N0 = r1 * temp;
    float saved = l2 * temp;
    temp = N1 * rcp21;
    N1 = saved + r2 * temp;
    float N2 = x * temp;
    float rcp30 = __builtin_amdgcn_rcpf(ft + 1.0f - km2);
    float rcp31 = __builtin_amdgcn_rcpf(kp2 - km1);
    float rcp32 = __builtin_amdgcn_rcpf(kp3 - ft);
    temp = N0 * rcp30;
    N0 = r1 * temp;
    saved = l3 * temp;
    temp = N1 * rcp31;
    N1 = saved + r2 * temp;
    saved = l2 * temp;
    temp = N2 * rcp32;
    N2 = saved + r3 * temp;
    N[0] = N0; N[1] = N1; N[2] = N2; N[3] = x * temp;
}

__device__ __forceinline__ unsigned char quant8(float v) {
    float b = fminf(fmaxf(rintf(v * INV_SCALE) + 128.0f, 0.0f), 255.0f);
    return (unsigned char)(int)b;
}

// Fused repack (unchanged from round 10, verified).
// A: L=(zb*29+yw)*29+x0, zb 0..30; beta: c=b>>4, rem=b&15, comp=rem&1,
//    jk=rem>>1, k=jk&1, j=jk>>1 -> (x0+c, yw+j, zb+k), comp in {cx,cy}.
// B: L=(zw*29+yw)*29+x0, zw 0..28; beta: c=b>>4, rem=b&15, j=rem>>2, k=rem&3.
__global__ void __launch_bounds__(256) repack_q8(const float* __restrict__ cp,
                                                 unsigned char* __restrict__ tabA,
                                                 unsigned char* __restrict__ tabB,
                                                 int nA, int nTot) {
    int i = blockIdx.x * blockDim.x + threadIdx.x;
    if (i >= nTot) return;
    float v;
    unsigned char* dst;
    if (i < nA) {
        int beta = i & 63, L = i >> 6;
        int x0 = L % NSEG;
        int t2 = L / NSEG;
        int yw = t2 % NSEG;
        int zb = t2 / NSEG;
        int c = beta >> 4, rem = beta & 15;
        int comp = rem & 1, jk = rem >> 1, k = jk & 1, j = jk >> 1;
        int src = ((zb + k) * NCTRL + (yw + j)) * NCTRL + (x0 + c);
        v = cp[3 * src + comp];
        dst = tabA + i;
    } else {
        int ii = i - nA;
        int beta = ii & 63, L = ii >> 6;
        int x0 = L % NSEG;
        int t2 = L / NSEG;
        int yw = t2 % NSEG;
        int zw = t2 / NSEG;
        int c = beta >> 4, rem = beta & 15;
        int j = rem >> 2, k = rem & 3;
        int src = ((zw + k) * NCTRL + (yw + j)) * NCTRL + (x0 + c);
        v = cp[3 * src + 2];
        dst = tabB + ii;
    }
    *dst = quant8(v);
}

// ---- staged 1-lane-per-query eval ------------------------------------------

#define LINE_STRIDE 1040                  // 1024 + 16B pad: bank-slot rotate
#define WAVE_STRIDE (12 * LINE_STRIDE)    // 12,480 B per wave

__device__ __forceinline__ void stage16(const unsigned char* src,
                                        unsigned char* dst_wave_uniform) {
#if defined(__has_builtin) && __has_builtin(__builtin_amdgcn_global_load_lds)
    // HW writes lane l's 16B at dst + l*16 (linear-by-lane dest);
    // global source address is per-lane.
    __builtin_amdgcn_global_load_lds(
        (const __attribute__((address_space(1))) void*)src,
        (__attribute__((address_space(3))) void*)dst_wave_uniform, 16, 0, 0);
#else
    // fallback: reg round-trip with explicit lane offset
    int lane = threadIdx.x & 63;
    *(u32x4*)(dst_wave_uniform + lane * 16) = *(const u32x4*)src;
#endif
}

// One lane per query. Wave stages 64 queries x 3 lines (A z-pair0, A z-pair1,
// B) via 12 quad-coherent global_load_lds, then each lane evaluates its own
// query from its LDS row. Staging instr i = ln*4 + grp; lane l fetches
// query (grp*16 + (l>>2)), chunk (l&3) -> eval lane g reads chunk (ln,x) at
// (ln*4 + (g>>4))*1040 + (g&15)*64 + x*16. (Verified: lane 37, ln=1, x=3 ->
// staged by instr 6, lane 23, query 37, chunk 3.)
__global__ void __launch_bounds__(256) spline_eval_q8v2(const float* __restrict__ q,
                                                        const unsigned char* __restrict__ tabA,
                                                        const unsigned char* __restrict__ tabB,
                                                        float* __restrict__ out, int Q) {
    __shared__ unsigned char smem[4 * WAVE_STRIDE];  // 49,920 B (4 waves)
    int t = blockIdx.x * blockDim.x + threadIdx.x;
    bool valid = t < Q;
    int g = valid ? t : (Q - 1);        // clamp: keep full waves (bpermute!)
    int lane = threadIdx.x & 63;
    int wid = __builtin_amdgcn_readfirstlane((int)(threadIdx.x >> 6));
    unsigned char* wbase = &smem[wid * WAVE_STRIDE];

    // own query coords + spans
    const float* qp = q + 3 * (size_t)g;
    float qx = qp[0], qy = qp[1], qz = qp[2];
    float Ux = qx * (float)NSEG, Uy = qy * (float)NSEG, Uz = qz * (float)NSEG;
    float fx = fminf(fmaxf(floorf(Ux), 0.0f), (float)(NSEG - 1));
    float fy = fminf(fmaxf(floorf(Uy), 0.0f), (float)(NSEG - 1));
    float fz = fminf(fmaxf(floorf(Uz), 0.0f), (float)(NSEG - 1));
    int sx = (int)fx, sy = (int)fy, sz = (int)fz;
    int L = (sz * NSEG + sy) * NSEG + sx;

    // redistribute L: staging instr with grp g2 needs L of query g2*16+(l>>2)
    int bidx = lane & 60;                 // ((lane>>2) << 2) byte index
    int sub16 = (lane & 3) << 4;          // chunk byte offset within line
    unsigned voff[4];
#pragma unroll
    for (int grp = 0; grp < 4; ++grp) {
        int Lg = __builtin_amdgcn_ds_bpermute((grp << 6) + bidx, L);
        voff[grp] = ((unsigned)Lg << 6) + (unsigned)sub16;
    }

    // 12 staged line-gathers (each = 16 x 64B-line requests, 3 lines/query)
#pragma unroll
    for (int i = 0; i < 12; ++i) {
        int ln = i >> 2, grp = i & 3;
        const unsigned char* src =
            (ln == 2 ? tabB : tabA + (ln == 1 ? 107648u : 0u)) + voff[grp];
        stage16(src, wbase + i * LINE_STRIDE);
    }

    // basis + weights while staging loads are in flight
    float Bx[4], By[4], Bz[4];
    basis_w(Ux, fx, Bx);
    basis_w(Uy, fy, By);
    basis_w(Uz, fz, Bz);

    h2 Bz01 = pkrtz(Bz[0], Bz[1]);
    h2 Bz23 = pkrtz(Bz[2], Bz[3]);
    const h2 one2 = {(_Float16)1.0f, (_Float16)1.0f};
    h2 wpk[4][2];
    float sumw = 0.0f;
#pragma unroll
    for (int j = 0; j < 4; ++j) {
        h2 Byj = pkrtz(By[j], By[j]);
        wpk[j][0] = Byj * Bz01;
        wpk[j][1] = Byj * Bz23;
        sumw = fdot2f(wpk[j][0], one2, sumw);
        sumw = fdot2f(wpk[j][1], one2, sumw);
    }

    const unsigned char* cbase =
        wbase + (lane >> 4) * LINE_STRIDE + (lane & 15) * 64;

    // A lines (staging instrs 0..7) done once <=4 outstanding (B instrs 8..11)
    asm volatile("s_waitcnt vmcnt(4)" ::: "memory");
    float axs[4], ays[4], azs[4];
#pragma unroll
    for (int x = 0; x < 4; ++x) {
        u32x4 c0 = *(const u32x4*)(cbase + 0 * 4 * LINE_STRIDE + x * 16);
        u32x4 c1 = *(const u32x4*)(cbase + 1 * 4 * LINE_STRIDE + x * 16);
        float ax = 0.0f, ay = 0.0f;
#pragma unroll
        for (int j = 0; j < 4; ++j) {
            unsigned d = c0[j];   // [cx(k0),cy(k0),cx(k1),cy(k1)]
            ax = fdot2f(permh(d, 0x04020400u), wpk[j][0], ax);
            ay = fdot2f(permh(d, 0x04030401u), wpk[j][0], ay);
            d = c1[j];            // same, z-pair {2,3}
            ax = fdot2f(permh(d, 0x04020400u), wpk[j][1], ax);
            ay = fdot2f(permh(d, 0x04030401u), wpk[j][1], ay);
        }
        axs[x] = ax; ays[x] = ay;
    }

    asm volatile("s_waitcnt vmcnt(0)" ::: "memory");
#pragma unroll
    for (int x = 0; x < 4; ++x) {
        u32x4 cb = *(const u32x4*)(cbase + 2 * 4 * LINE_STRIDE + x * 16);
        float az = 0.0f;
#pragma unroll
        for (int j = 0; j < 4; ++j) {
            unsigned d = cb[j];   // [cz(k0),cz(k1),cz(k2),cz(k3)]
            az = fdot2f(permh(d, 0x04010400u), wpk[j][0], az);
            az = fdot2f(permh(d, 0x04030402u), wpk[j][1], az);
        }
        azs[x] = az;
    }

    // fold Bx and the 1152 fp16 bias (value = 1024 + (q+128) = 1152 + qv)
    float vx = 0.0f, vy = 0.0f, vz = 0.0f;
#pragma unroll
    for (int x = 0; x < 4; ++x) {
        vx = fmaf(Bx[x], axs[x], vx);
        vy = fmaf(Bx[x], ays[x], vy);
        vz = fmaf(Bx[x], azs[x], vz);
    }
    float mb = (-1152.0f * SCALE) * sumw;   // sum(Bx) == 1 (partition of unity)
    vx = fmaf(vx, SCALE, mb);
    vy = fmaf(vy, SCALE, mb);
    vz = fmaf(vz, SCALE, mb);
    if (valid) {
        out[3 * (size_t)g + 0] = vx;
        out[3 * (size_t)g + 1] = vy;
        out[3 * (size_t)g + 2] = vz;
    }
}

// Fallback: direct [n,3]-layout gather per thread (no workspace needed).
__global__ void __launch_bounds__(256) spline_eval_direct(const float* __restrict__ q,
                                                          const float* __restrict__ cp,
                                                          float* __restrict__ out, int Q) {
    int idx = blockIdx.x * blockDim.x + threadIdx.x;
    if (idx >= Q) return;
    float U[3], ft[3];
    int s[3];
#pragma unroll
    for (int d = 0; d < 3; ++d) {
        U[d]  = q[3 * idx + d] * (float)NSEG;
        ft[d] = fminf(fmaxf(floorf(U[d]), 0.0f), (float)(NSEG - 1));
        s[d]  = (int)ft[d];
    }
    float Bx[4], By[4], Bz[4];
    basis_w(U[0], ft[0], Bx);
    basis_w(U[1], ft[1], By);
    basis_w(U[2], ft[2], Bz);
    float ax = 0.f, ay = 0.f, az = 0.f;
#pragma unroll
    for (int k = 0; k < 4; ++k) {
#pragma unroll
        for (int j = 0; j < 4; ++j) {
            float w = Bz[k] * By[j];
            int base = ((s[2] + k) * NCTRL + (s[1] + j)) * NCTRL + s[0];
#pragma unroll
            for (int i = 0; i < 4; ++i) {
                float wi = w * Bx[i];
                ax = fmaf(wi, cp[3 * (base + i) + 0], ax);
                ay = fmaf(wi, cp[3 * (base + i) + 1], ay);
                az = fmaf(wi, cp[3 * (base + i) + 2], az);
            }
        }
    }
    out[3 * idx + 0] = ax;
    out[3 * idx + 1] = ay;
    out[3 * idx + 2] = az;
}

extern "C" void kernel_launch(void* const* d_in, const int* in_sizes, int n_in,
                              void* d_out, int out_size, void* d_ws, size_t ws_size,
                              hipStream_t stream) {
    const float* q  = (const float*)d_in[0];
    const float* cp = (const float*)d_in[1];
    float* out = (float*)d_out;
    int Q = in_sizes[0] / 3;

    const int nA = 31 * NSEG * NSEG * 64;    // 1,668,544 bytes
    const int nB = NSEG * NSEG * NSEG * 64;  // 1,560,896 bytes
    const int nTot = nA + nB;
    if (ws_size >= (size_t)nTot) {
        unsigned char* tabA = (unsigned char*)d_ws;
        unsigned char* tabB = tabA + nA;     // nA is 64B-aligned
        repack_q8<<<(nTot + 255) / 256, 256, 0, stream>>>(cp, tabA, tabB, nA, nTot);
        spline_eval_q8v2<<<(Q + 255) / 256, 256, 0, stream>>>(q, tabA, tabB, out, Q);
    } else {
        spline_eval_direct<<<(Q + 255) / 256, 256, 0, stream>>>(q, cp, out, Q);
    }
}

// Round 2
// 110.165 us; speedup vs baseline: 1.0788x; 1.0429x over previous
//
#include <hip/hip_runtime.h>

// Tricubic B-spline evaluation, p=3, n_ctrl=32 per dim, open-uniform knots.
// queries: [Q,3] f32 in [0,1); control_points: [32^3, 3] f32; out: [Q,3] f32.
//
// Round 14: occupancy fix. Round 13 staged all 12 lines/wave (12,480 B LDS
// -> 3 blocks/CU = 3 waves/SIMD) and went latency-bound. Now one 4-line
// buffer per wave (4,160 B -> 16,640 B/block -> 8 blocks/CU) rotated through
// three phases A0 -> A1 -> B: wait vmcnt(0), ds_read phase data to regs,
// lgkmcnt(0)+sched_barrier (LDS reuse fence), re-stage next phase into the
// same slots, compute under its latency. Same 3 line-lookups/query, same
// numerics as round 12/13 (int8 tables, byte->fp16 via v_perm 0x6400|b,
// v_dot2_f32_f16 core, sumw bias cancellation).
// Repack vectorized 4x: one thread = 4 table bytes = 1 dword store.

#define NCTRL 32
#define NSEG 29
#define SCALE (5.5f / 127.0f)
#define INV_SCALE (127.0f / 5.5f)

typedef unsigned int u32x4 __attribute__((ext_vector_type(4)));
typedef _Float16 h2 __attribute__((ext_vector_type(2)));
using native_h2 = decltype(__builtin_amdgcn_cvt_pkrtz(0.0f, 0.0f));

__device__ __forceinline__ h2 pkrtz(float a, float b) {
    return __builtin_bit_cast(h2, __builtin_amdgcn_cvt_pkrtz(a, b));
}
__device__ __forceinline__ float fdot2f(h2 a, h2 b, float c) {
    return __builtin_amdgcn_fdot2(__builtin_bit_cast(native_h2, a),
                                  __builtin_bit_cast(native_h2, b), c, false);
}
__device__ __forceinline__ h2 permh(unsigned int d, unsigned int sel) {
    return __builtin_bit_cast(h2, __builtin_amdgcn_perm(0x64646464u, d, sel));
}

// Division-free Cox-de Boor weights in knot units (scale-invariant).
__device__ __forceinline__ void basis_w(float U, float ft, float N[4]) {
    float x  = U - ft;
    float r1 = 1.0f - x;
    float km1 = fmaxf(ft - 1.0f, 0.0f);
    float km2 = fmaxf(ft - 2.0f, 0.0f);
    float kp2 = fminf(ft + 2.0f, (float)NSEG);
    float kp3 = fminf(ft + 3.0f, (float)NSEG);
    float l2 = U - km1, l3 = U - km2;
    float r2 = kp2 - U, r3 = kp3 - U;
    float N0 = r1, N1 = x;
    float rcp20 = __builtin_amdgcn_rcpf(ft + 1.0f - km1);
    float rcp21 = __builtin_amdgcn_rcpf(kp2 - ft);
    float temp  = N0 * rcp20;
    N0 = r1 * temp;
    float saved = l2 * temp;
    temp = N1 * rcp21;
    N1 = saved + r2 * temp;
    float N2 = x * temp;
    float rcp30 = __builtin_amdgcn_rcpf(ft + 1.0f - km2);
    float rcp31 = __builtin_amdgcn_rcpf(kp2 - km1);
    float rcp32 = __builtin_amdgcn_rcpf(kp3 - ft);
    temp = N0 * rcp30;
    N0 = r1 * temp;
    saved = l3 * temp;
    temp = N1 * rcp31;
    N1 = saved + r2 * temp;
    saved = l2 * temp;
    temp = N2 * rcp32;
    N2 = saved + r3 * temp;
    N[0] = N0; N[1] = N1; N[2] = N2; N[3] = x * temp;
}

__device__ __forceinline__ unsigned char quant8(float v) {
    float b = fminf(fmaxf(rintf(v * INV_SCALE) + 128.0f, 0.0f), 255.0f);
    return (unsigned char)(int)b;
}

// Vectorized repack: one thread emits 4 consecutive table bytes (one dword).
// Within an aligned 4-byte group, L, c, j are constant:
//  A: beta=c<<4|rem, rem bits: comp=b&1, k=(b>>1)&1, j=rem>>2.
//     bytes = {cp[3s+0], cp[3s+1], cp[3(s+1024)+0], cp[3(s+1024)+1]},
//     s = (zb*32 + yw+j)*32 + x0+c.
//  B: rem bits: k=rem&3 (=byte idx), j=rem>>2. bytes = cp[3(s+b*1024)+2].
__global__ void __launch_bounds__(256) repack_q8v2(const float* __restrict__ cp,
                                                   unsigned char* __restrict__ tabA,
                                                   unsigned char* __restrict__ tabB,
                                                   int nA, int nTot) {
    int i4 = blockIdx.x * blockDim.x + threadIdx.x;
    int ib = i4 * 4;
    if (ib >= nTot) return;
    unsigned int w;
    unsigned int* dst;
    if (ib < nA) {
        int beta = ib & 63, L = ib >> 6;
        int x0 = L % NSEG;
        int t2 = L / NSEG;
        int yw = t2 % NSEG;
        int zb = t2 / NSEG;
        int c = beta >> 4, j = (beta & 15) >> 2;
        int s = (zb * NCTRL + (yw + j)) * NCTRL + (x0 + c);
        unsigned int b0 = quant8(cp[3 * s + 0]);
        unsigned int b1 = quant8(cp[3 * s + 1]);
        unsigned int b2 = quant8(cp[3 * (s + NCTRL * NCTRL) + 0]);
        unsigned int b3 = quant8(cp[3 * (s + NCTRL * NCTRL) + 1]);
        w = b0 | (b1 << 8) | (b2 << 16) | (b3 << 24);
        dst = (unsigned int*)(tabA + ib);
    } else {
        int ii = ib - nA;
        int beta = ii & 63, L = ii >> 6;
        int x0 = L % NSEG;
        int t2 = L / NSEG;
        int yw = t2 % NSEG;
        int zw = t2 / NSEG;
        int c = beta >> 4, j = (beta & 15) >> 2;
        int s = (zw * NCTRL + (yw + j)) * NCTRL + (x0 + c);
        unsigned int b0 = quant8(cp[3 * (s + 0 * NCTRL * NCTRL) + 2]);
        unsigned int b1 = quant8(cp[3 * (s + 1 * NCTRL * NCTRL) + 2]);
        unsigned int b2 = quant8(cp[3 * (s + 2 * NCTRL * NCTRL) + 2]);
        unsigned int b3 = quant8(cp[3 * (s + 3 * NCTRL * NCTRL) + 2]);
        w = b0 | (b1 << 8) | (b2 << 16) | (b3 << 24);
        dst = (unsigned int*)(tabB + ii);
    }
    *dst = w;
}

// ---- staged 1-lane-per-query eval, 3-phase rotating 4-line buffer ---------

#define LINE_STRIDE 1040                 // 1024 + 16B pad: bank-slot rotate
#define WAVE_LDS (4 * LINE_STRIDE)       // 4,160 B per wave

__device__ __forceinline__ void stage16(const unsigned char* src,
                                        unsigned char* dst_wave_uniform) {
    // HW writes lane l's 16B at dst + l*16 (linear-by-lane dest);
    // global source address is per-lane.
    __builtin_amdgcn_global_load_lds(
        (const __attribute__((address_space(1))) void*)src,
        (__attribute__((address_space(3))) void*)dst_wave_uniform, 16, 0, 0);
}

// One lane per query. Per phase, 4 staging instrs cover 64 queries x 1 line
// (lane l of instr grp fetches query grp*16+(l>>2), chunk l&3). Eval lane g
// reads its line at slot (g>>4)*1040 + (g&15)*64. Buffer is reused across
// phases A0 (z-pair {0,1}), A1 (z-pair {2,3}), B; the lgkmcnt(0)+
// sched_barrier fence before each re-stage guarantees the reads drained.
__global__ void __launch_bounds__(256, 6) spline_eval_q8v3(const float* __restrict__ q,
                                                           const unsigned char* __restrict__ tabA,
                                                           const unsigned char* __restrict__ tabB,
                                                           float* __restrict__ out, int Q) {
    __shared__ unsigned char smem[4 * WAVE_LDS];   // 16,640 B (4 waves)
    int t = blockIdx.x * blockDim.x + threadIdx.x;
    bool valid = t < Q;
    int g = valid ? t : (Q - 1);        // clamp: keep full waves (bpermute!)
    int lane = threadIdx.x & 63;
    unsigned char* wbase = &smem[(threadIdx.x >> 6) * WAVE_LDS];

    // own query coords + spans
    const float* qp = q + 3 * (size_t)g;
    float qx = qp[0], qy = qp[1], qz = qp[2];
    float Ux = qx * (float)NSEG, Uy = qy * (float)NSEG, Uz = qz * (float)NSEG;
    float fx = fminf(fmaxf(floorf(Ux), 0.0f), (float)(NSEG - 1));
    float fy = fminf(fmaxf(floorf(Uy), 0.0f), (float)(NSEG - 1));
    float fz = fminf(fmaxf(floorf(Uz), 0.0f), (float)(NSEG - 1));
    int sx = (int)fx, sy = (int)fy, sz = (int)fz;
    int L = (sz * NSEG + sy) * NSEG + sx;

    // redistribute L: staging instr grp needs L of query grp*16+(l>>2)
    int bidx = lane & 60;                 // ((lane>>2) << 2) byte index
    int sub16 = (lane & 3) << 4;          // chunk byte offset within line
    unsigned voff[4];
#pragma unroll
    for (int grp = 0; grp < 4; ++grp) {
        int Lg = __builtin_amdgcn_ds_bpermute((grp << 6) + bidx, L);
        voff[grp] = ((unsigned)Lg << 6) + (unsigned)sub16;
    }

    // stage phase A0 (z-pair {0,1})
#pragma unroll
    for (int grp = 0; grp < 4; ++grp)
        stage16(tabA + voff[grp], wbase + grp * LINE_STRIDE);

    // basis + weights while A0 is in flight
    float Bx[4], By[4], Bz[4];
    basis_w(Ux, fx, Bx);
    basis_w(Uy, fy, By);
    basis_w(Uz, fz, Bz);

    h2 Bz01 = pkrtz(Bz[0], Bz[1]);
    h2 Bz23 = pkrtz(Bz[2], Bz[3]);
    const h2 one2 = {(_Float16)1.0f, (_Float16)1.0f};
    h2 wpk[4][2];
    float sumw = 0.0f;
#pragma unroll
    for (int j = 0; j < 4; ++j) {
        h2 Byj = pkrtz(By[j], By[j]);
        wpk[j][0] = Byj * Bz01;
        wpk[j][1] = Byj * Bz23;
        sumw = fdot2f(wpk[j][0], one2, sumw);
        sumw = fdot2f(wpk[j][1], one2, sumw);
    }

    const unsigned char* cbase =
        wbase + (lane >> 4) * LINE_STRIDE + (lane & 15) * 64;

    u32x4 c[4];
    float axs[4], ays[4];

    // ---- phase 0: consume A0, re-stage A1 into same slots
    asm volatile("s_waitcnt vmcnt(0)" ::: "memory");
#pragma unroll
    for (int x = 0; x < 4; ++x) c[x] = *(const u32x4*)(cbase + x * 16);
    asm volatile("s_waitcnt lgkmcnt(0)" ::: "memory");
    __builtin_amdgcn_sched_barrier(0);
#pragma unroll
    for (int grp = 0; grp < 4; ++grp)
        stage16(tabA + 107648u + voff[grp], wbase + grp * LINE_STRIDE);
#pragma unroll
    for (int x = 0; x < 4; ++x) {
        float ax = 0.0f, ay = 0.0f;
#pragma unroll
        for (int j = 0; j < 4; ++j) {
            unsigned d = c[x][j];   // [cx(k0),cy(k0),cx(k1),cy(k1)]
            ax = fdot2f(permh(d, 0x04020400u), wpk[j][0], ax);
            ay = fdot2f(permh(d, 0x04030401u), wpk[j][0], ay);
        }
        axs[x] = ax; ays[x] = ay;
    }

    // ---- phase 1: consume A1, re-stage B into same slots
    asm volatile("s_waitcnt vmcnt(0)" ::: "memory");
#pragma unroll
    for (int x = 0; x < 4; ++x) c[x] = *(const u32x4*)(cbase + x * 16);
    asm volatile("s_waitcnt lgkmcnt(0)" ::: "memory");
    __builtin_amdgcn_sched_barrier(0);
#pragma unroll
    for (int grp = 0; grp < 4; ++grp)
        stage16(tabB + voff[grp], wbase + grp * LINE_STRIDE);
#pragma unroll
    for (int x = 0; x < 4; ++x) {
        float ax = axs[x], ay = ays[x];
#pragma unroll
        for (int j = 0; j < 4; ++j) {
            unsigned d = c[x][j];   // same layout, z-pair {2,3}
            ax = fdot2f(permh(d, 0x04020400u), wpk[j][1], ax);
            ay = fdot2f(permh(d, 0x04030401u), wpk[j][1], ay);
        }
        axs[x] = ax; ays[x] = ay;
    }

    // ---- phase 2: consume B
    asm volatile("s_waitcnt vmcnt(0)" ::: "memory");
#pragma unroll
    for (int x = 0; x < 4; ++x) c[x] = *(const u32x4*)(cbase + x * 16);
    float vz = 0.0f;
#pragma unroll
    for (int x = 0; x < 4; ++x) {
        float az = 0.0f;
#pragma unroll
        for (int j = 0; j < 4; ++j) {
            unsigned d = c[x][j];   // [cz(k0),cz(k1),cz(k2),cz(k3)]
            az = fdot2f(permh(d, 0x04010400u), wpk[j][0], az);
            az = fdot2f(permh(d, 0x04030402u), wpk[j][1], az);
        }
        vz = fmaf(Bx[x], az, vz);
    }

    // fold Bx and the 1152 fp16 bias (value = 1024 + (q+128) = 1152 + qv)
    float vx = 0.0f, vy = 0.0f;
#pragma unroll
    for (int x = 0; x < 4; ++x) {
        vx = fmaf(Bx[x], axs[x], vx);
        vy = fmaf(Bx[x], ays[x], vy);
    }
    float mb = (-1152.0f * SCALE) * sumw;   // sum(Bx) == 1 (partition of unity)
    vx = fmaf(vx, SCALE, mb);
    vy = fmaf(vy, SCALE, mb);
    vz = fmaf(vz, SCALE, mb);
    if (valid) {
        out[3 * (size_t)g + 0] = vx;
        out[3 * (size_t)g + 1] = vy;
        out[3 * (size_t)g + 2] = vz;
    }
}

// Fallback: direct [n,3]-layout gather per thread (no workspace needed).
__global__ void __launch_bounds__(256) spline_eval_direct(const float* __restrict__ q,
                                                          const float* __restrict__ cp,
                                                          float* __restrict__ out, int Q) {
    int idx = blockIdx.x * blockDim.x + threadIdx.x;
    if (idx >= Q) return;
    float U[3], ft[3];
    int s[3];
#pragma unroll
    for (int d = 0; d < 3; ++d) {
        U[d]  = q[3 * idx + d] * (float)NSEG;
        ft[d] = fminf(fmaxf(floorf(U[d]), 0.0f), (float)(NSEG - 1));
        s[d]  = (int)ft[d];
    }
    float Bx[4], By[4], Bz[4];
    basis_w(U[0], ft[0], Bx);
    basis_w(U[1], ft[1], By);
    basis_w(U[2], ft[2], Bz);
    float ax = 0.f, ay = 0.f, az = 0.f;
#pragma unroll
    for (int k = 0; k < 4; ++k) {
#pragma unroll
        for (int j = 0; j < 4; ++j) {
            float w = Bz[k] * By[j];
            int base = ((s[2] + k) * NCTRL + (s[1] + j)) * NCTRL + s[0];
#pragma unroll
            for (int i = 0; i < 4; ++i) {
                float wi = w * Bx[i];
                ax = fmaf(wi, cp[3 * (base + i) + 0], ax);
                ay = fmaf(wi, cp[3 * (base + i) + 1], ay);
                az = fmaf(wi, cp[3 * (base + i) + 2], az);
            }
        }
    }
    out[3 * idx + 0] = ax;
    out[3 * idx + 1] = ay;
    out[3 * idx + 2] = az;
}

extern "C" void kernel_launch(void* const* d_in, const int* in_sizes, int n_in,
                              void* d_out, int out_size, void* d_ws, size_t ws_size,
                              hipStream_t stream) {
    const float* q  = (const float*)d_in[0];
    const float* cp = (const float*)d_in[1];
    float* out = (float*)d_out;
    int Q = in_sizes[0] / 3;

    const int nA = 31 * NSEG * NSEG * 64;    // 1,668,544 bytes (dword-aligned)
    const int nB = NSEG * NSEG * NSEG * 64;  // 1,560,896 bytes
    const int nTot = nA + nB;
    if (ws_size >= (size_t)nTot) {
        unsigned char* tabA = (unsigned char*)d_ws;
        unsigned char* tabB = tabA + nA;     // nA is 64B-aligned
        int n4 = nTot / 4;
        repack_q8v2<<<(n4 + 255) / 256, 256, 0, stream>>>(cp, tabA, tabB, nA, nTot);
        spline_eval_q8v3<<<(Q + 255) / 256, 256, 0, stream>>>(q, tabA, tabB, out, Q);
    } else {
        spline_eval_direct<<<(Q + 255) / 256, 256, 0, stream>>>(q, cp, out, Q);
    }
}